// Round 7
// baseline (167.737 us; speedup 1.0000x reference)
//
#include <hip/hip_runtime.h>

// CompositeLoss R18: split pin + high occupancy (the untried corner).
// R15/R16/R17 post-mortem: three structural nulls at ~40us with in-flight
// loads 252/280/252 per CU -- every MLP gain was paid for with occupancy
// (R14: 11 waves/CU, R16/R17: 8). With L2+L3 flushed by the harness's
// 256MB poison fills, first-touch latency ~900-1200cy; at 2.75-3 waves/
// SIMD the SIMD idles whenever its waves all wait (every pipe ~25% busy,
// R14 profile). R18 keeps ONLY the far loads pinned (own+d: 14 f4 = 56
// VGPR) and lets the L1-hit h-loads sink, so peak liveness ~81 VGPR fits
// __launch_bounds__(256,6) -> 6 waves/SIMD (24/CU, 2x R15) with 336 far
// loads in flight per CU. Hiding capacity 5x1400cy >> 1200cy latency.
// Tripwires: VGPR_Count 80-85 (else bound ignored); WRITE_SIZE ~1MB
// (>>1MB = spill -> revert to R15).
// Partial rows: 4 waves/block * 4096 blocks = 16384 rows of 16.
//  0:M 1:Mx(d) 2:My(h) 3:Mz(w)  4:Smae 5:Smse 6:Sbg
//  7:Sgx 8:Sgy 9:Sgz  10:Stx 11:Sty 12:Stz
#define NACC 13
#define NPAD 16
#define NBLOCKS 4096   // 2^20 groups / 256
#define NROWS 16384    // NBLOCKS * 4 waves
#define NMID 64        // 16384 / 256

__device__ __forceinline__ float4 ld4(const float* p) {
    return *reinterpret_cast<const float4*>(p);
}

__global__ __launch_bounds__(256, 6) void loss_main(
    const float* __restrict__ pred, const float* __restrict__ target,
    const float* __restrict__ mask, float* __restrict__ partials)
{
    float acc[NACC];
#pragma unroll
    for (int k = 0; k < NACC; ++k) acc[k] = 0.f;

    // one group per thread: group = (b, d, h, w4); mapping identical to R11
    const int g  = blockIdx.x * 256 + threadIdx.x;
    const int w4 = g & 31;
    const int h  = (g >> 5) & 127;
    const int d  = (g >> 12) & 127;
    const int b  = g >> 19;
    const int w  = w4 << 2;
    const int mb  = b * 2097152 + d * 16384 + h * 128 + w; // mask index
    const int pb0 = b * 6291456 + d * 16384 + h * 128 + w; // pred/target base

    // boundary: clamp offsets in-bounds; flags zero the affected masks
    const float wv = (w4 < 31) ? 1.f : 0.f;
    const float hv = (h < 127) ? 1.f : 0.f;
    const float dv = (d < 127) ? 1.f : 0.f;
    const int oh = (h < 127) ? 128   : 0;
    const int od = (d < 127) ? 16384 : 0;

    // ---- pin ONLY the far loads (own row + d-neighbor, 14 f4 = 56 VGPR):
    // these are the post-poison L2/HBM misses that need deep MLP. The
    // h-loads (+512B, line-shared with neighbor waves -> L1 hits) are NOT
    // pinned so their registers don't count against the 85-VGPR budget.
    const float4 m0 = ld4(mask + mb);
    const float4 md = ld4(mask + mb + od);
    float4 P0[3], T0[3], PD[3], TD[3];
#pragma unroll
    for (int c = 0; c < 3; ++c) {
        const int pb = pb0 + c * 2097152;
        P0[c] = ld4(pred + pb);       T0[c] = ld4(target + pb);
        PD[c] = ld4(pred + pb + od);  TD[c] = ld4(target + pb + od);
    }
    __builtin_amdgcn_sched_barrier(0);   // far loads may not sink past here

    const float4 mh = ld4(mask + mb + oh);   // short-latency, unpinned

    const float m4w = __shfl_down(m0.x, 1, 64);  // lane w4=31: garbage, wv=0

    // pairwise mins (binary mask -> AND); boundary flags kill clamped terms
    const float mz0 = fminf(m0.x, m0.y), mz1 = fminf(m0.y, m0.z),
                mz2 = fminf(m0.z, m0.w), mz3 = fminf(m0.w, m4w) * wv;
    const float my0 = fminf(m0.x, mh.x) * hv, my1 = fminf(m0.y, mh.y) * hv,
                my2 = fminf(m0.z, mh.z) * hv, my3 = fminf(m0.w, mh.w) * hv;
    const float mx0 = fminf(m0.x, md.x) * dv, mx1 = fminf(m0.y, md.y) * dv,
                mx2 = fminf(m0.z, md.z) * dv, mx3 = fminf(m0.w, md.w) * dv;

    acc[0] = m0.x + m0.y + m0.z + m0.w;
    acc[1] = mx0 + mx1 + mx2 + mx3;
    acc[2] = my0 + my1 + my2 + my3;
    acc[3] = mz0 + mz1 + mz2 + mz3;

#pragma unroll
    for (int c = 0; c < 3; ++c) {
        const int pb = pb0 + c * 2097152;
        const float4 ph = ld4(pred + pb + oh);     // unpinned, L1-hit
        const float4 th = ld4(target + pb + oh);
        const float4 p0 = P0[c], t0 = T0[c];
        const float4 pd = PD[c], td = TD[c];
        const float  p4 = __shfl_down(p0.x, 1, 64);  // w-neighbor from lane+1
        const float  t4 = __shfl_down(t0.x, 1, 64);

        const float e0x = p0.x - t0.x, e0y = p0.y - t0.y,
                    e0z = p0.z - t0.z, e0w = p0.w - t0.w;
        const float e4  = p4 - t4;

        acc[4] += fabsf(e0x)*m0.x + fabsf(e0y)*m0.y
                + fabsf(e0z)*m0.z + fabsf(e0w)*m0.w;
        acc[5] += e0x*e0x*m0.x + e0y*e0y*m0.y
                + e0z*e0z*m0.z + e0w*e0w*m0.w;
        acc[6] += fabsf(p0.x)*(1.f-m0.x) + fabsf(p0.y)*(1.f-m0.y)
                + fabsf(p0.z)*(1.f-m0.z) + fabsf(p0.w)*(1.f-m0.w);

        // W direction (reference dz); mz3=0 at w-boundary kills shfl garbage
        acc[9]  += fabsf(e0y-e0x)*mz0 + fabsf(e0z-e0y)*mz1
                 + fabsf(e0w-e0z)*mz2 + fabsf(e4 -e0w)*mz3;
        acc[12] += fabsf(p0.y-p0.x)*mz0 + fabsf(p0.z-p0.y)*mz1
                 + fabsf(p0.w-p0.z)*mz2 + fabsf(p4  -p0.w)*mz3;

        // H direction (reference dy); my*=0 at h-boundary
        acc[8]  += fabsf((ph.x-th.x)-e0x)*my0 + fabsf((ph.y-th.y)-e0y)*my1
                 + fabsf((ph.z-th.z)-e0z)*my2 + fabsf((ph.w-th.w)-e0w)*my3;
        acc[11] += fabsf(ph.x-p0.x)*my0 + fabsf(ph.y-p0.y)*my1
                 + fabsf(ph.z-p0.z)*my2 + fabsf(ph.w-p0.w)*my3;

        // D direction (reference dx); mx*=0 at d-boundary
        acc[7]  += fabsf((pd.x-td.x)-e0x)*mx0 + fabsf((pd.y-td.y)-e0y)*mx1
                 + fabsf((pd.z-td.z)-e0z)*mx2 + fabsf((pd.w-td.w)-e0w)*mx3;
        acc[10] += fabsf(pd.x-p0.x)*mx0 + fabsf(pd.y-p0.y)*mx1
                 + fabsf(pd.z-p0.z)*mx2 + fabsf(pd.w-p0.w)*mx3;
    }

    // per-wave shuffle reduce -> own partials row; NO __syncthreads:
    // each wave retires as soon as its own tail drains.
    const int lane = threadIdx.x & 63;
    const int wave = threadIdx.x >> 6;
    float mine = 0.f;   // lane k (<16) ends up holding total of acc[k]
#pragma unroll
    for (int k = 0; k < NACC; ++k) {
        float v = acc[k];
        for (int o = 32; o > 0; o >>= 1) v += __shfl_down(v, o, 64);
        const float tot = __shfl(v, 0, 64);
        if (lane == k) mine = tot;
    }
    if (lane < NPAD)
        partials[(blockIdx.x * 4 + wave) * NPAD + lane] = mine; // pad rows=0
}

// Level 1: 64 blocks x 256 threads; thread r reads row r (4 independent
// float4), block-reduces 256 rows -> 1 row. 64 CUs share the 1 MiB read.
__global__ __launch_bounds__(256) void loss_mid(
    const float* __restrict__ partials, float* __restrict__ mid)
{
    const int r = blockIdx.x * 256 + threadIdx.x;   // exactly covers 16384
    const float* row = partials + r * NPAD;
    const float4 r0 = ld4(row);     const float4 r1 = ld4(row + 4);
    const float4 r2 = ld4(row + 8); const float4 r3 = ld4(row + 12);
    float acc[NPAD] = {r0.x, r0.y, r0.z, r0.w, r1.x, r1.y, r1.z, r1.w,
                       r2.x, r2.y, r2.z, r2.w, r3.x, r3.y, r3.z, r3.w};

    const int lane = threadIdx.x & 63;
    const int wave = threadIdx.x >> 6;
    __shared__ float red[4][NPAD];
#pragma unroll
    for (int k = 0; k < NPAD; ++k) {
        float v = acc[k];
        for (int o = 32; o > 0; o >>= 1) v += __shfl_down(v, o, 64);
        if (lane == 0) red[wave][k] = v;
    }
    __syncthreads();
    if (threadIdx.x < NPAD) {
        const int k = threadIdx.x;
        mid[blockIdx.x * NPAD + k] =
            red[0][k] + red[1][k] + red[2][k] + red[3][k];
    }
}

// Level 2: one wave; lane l reads mid row l (64 rows), shuffle-reduce,
// lane 0 does the scalar epilogue.
__global__ __launch_bounds__(64) void loss_final(
    const float* __restrict__ mid, float* __restrict__ out)
{
    const int lane = threadIdx.x;
    float acc[NPAD];
    {
        const float* row = mid + lane * NPAD;   // lane < 64 == NMID
        const float4 r0 = ld4(row);     const float4 r1 = ld4(row + 4);
        const float4 r2 = ld4(row + 8); const float4 r3 = ld4(row + 12);
        acc[0] = r0.x;  acc[1] = r0.y;  acc[2] = r0.z;  acc[3] = r0.w;
        acc[4] = r1.x;  acc[5] = r1.y;  acc[6] = r1.z;  acc[7] = r1.w;
        acc[8] = r2.x;  acc[9] = r2.y;  acc[10] = r2.z; acc[11] = r2.w;
        acc[12] = r3.x; acc[13] = r3.y; acc[14] = r3.z; acc[15] = r3.w;
    }
#pragma unroll
    for (int k = 0; k < NACC; ++k) {
        for (int o = 32; o > 0; o >>= 1) acc[k] += __shfl_down(acc[k], o, 64);
    }
    if (lane == 0) {
        const float EPS = 1e-8f;
        const float M = acc[0], Mx = acc[1], My = acc[2], Mz = acc[3];
        float loss = (acc[4] + acc[5]) / (3.f * M + EPS);   // W_MAE=1, W_MSE=1
        loss += 0.1f   * (acc[7] / (3.f*Mx + EPS) + acc[8] / (3.f*My + EPS)
                        + acc[9] / (3.f*Mz + EPS));
        loss += 0.002f * (acc[10] / (3.f*Mx + EPS) + acc[11] / (3.f*My + EPS)
                        + acc[12] / (3.f*Mz + EPS));
        const float inv = 4194304.f - M;  // B*D*H*W - M
        loss += 0.15f * acc[6] / (3.f * inv + EPS);
        out[0] = loss;
    }
}

extern "C" void kernel_launch(void* const* d_in, const int* in_sizes, int n_in,
                              void* d_out, int out_size, void* d_ws, size_t ws_size,
                              hipStream_t stream) {
    const float* pred   = (const float*)d_in[0];
    const float* target = (const float*)d_in[1];
    const float* mask   = (const float*)d_in[2];
    float* out      = (float*)d_out;
    float* partials = (float*)d_ws;                 // 16384*16 floats = 1 MiB
    float* mid      = partials + NROWS * NPAD;      // 64*16 floats

    loss_main<<<NBLOCKS, 256, 0, stream>>>(pred, target, mask, partials);
    loss_mid<<<NMID, 256, 0, stream>>>(partials, mid);
    loss_final<<<1, 64, 0, stream>>>(mid, out);
}

// Round 8
// 144.621 us; speedup vs baseline: 1.1598x; 1.1598x over previous
//
#include <hip/hip_runtime.h>

// CompositeLoss R19: far-pin + safe 128-VGPR cap (the last clean probe of
// the latency-hiding axis). R18 post-mortem: (256,6) made the allocator
// target ~12 waves/SIMD and SPILL the pinned far loads (VGPR=40, 70MB
// scratch writes, 68us). Occupancy itself DID rise to 56% -- the lever
// works; the spill killed it. R19: identical split pin (own+d rows, 14 f4
// = 56 VGPR pinned; h-loads unpinned/L1) but __launch_bounds__(256,4):
// cap 128 >> ~100 peak liveness, so no spill is rational; guaranteed 4
// waves/SIMD (+33% resident compute vs R15) to overlap the one far wait.
// Surface so far: (all-pin,3w)=40 (all-pin,2w x2/x4work)=40/40 (sunk)=45
// (far-pin,spill)=68. If this round is also ~40 clean, the 40us floor is
// structure-invariant -> declare roofline and revert to best.
// Tripwires: VGPR_Count 96-128 (=40 again means spilled); WRITE_SIZE ~1MB.
// Partial rows: 4 waves/block * 4096 blocks = 16384 rows of 16.
//  0:M 1:Mx(d) 2:My(h) 3:Mz(w)  4:Smae 5:Smse 6:Sbg
//  7:Sgx 8:Sgy 9:Sgz  10:Stx 11:Sty 12:Stz
#define NACC 13
#define NPAD 16
#define NBLOCKS 4096   // 2^20 groups / 256
#define NROWS 16384    // NBLOCKS * 4 waves
#define NMID 64        // 16384 / 256

__device__ __forceinline__ float4 ld4(const float* p) {
    return *reinterpret_cast<const float4*>(p);
}

__global__ __launch_bounds__(256, 4) void loss_main(
    const float* __restrict__ pred, const float* __restrict__ target,
    const float* __restrict__ mask, float* __restrict__ partials)
{
    float acc[NACC];
#pragma unroll
    for (int k = 0; k < NACC; ++k) acc[k] = 0.f;

    // one group per thread: group = (b, d, h, w4); mapping identical to R11
    const int g  = blockIdx.x * 256 + threadIdx.x;
    const int w4 = g & 31;
    const int h  = (g >> 5) & 127;
    const int d  = (g >> 12) & 127;
    const int b  = g >> 19;
    const int w  = w4 << 2;
    const int mb  = b * 2097152 + d * 16384 + h * 128 + w; // mask index
    const int pb0 = b * 6291456 + d * 16384 + h * 128 + w; // pred/target base

    // boundary: clamp offsets in-bounds; flags zero the affected masks
    const float wv = (w4 < 31) ? 1.f : 0.f;
    const float hv = (h < 127) ? 1.f : 0.f;
    const float dv = (d < 127) ? 1.f : 0.f;
    const int oh = (h < 127) ? 128   : 0;
    const int od = (d < 127) ? 16384 : 0;

    // ---- pin ONLY the far loads (own row + d-neighbor, 14 f4 = 56 VGPR):
    // these are the post-poison L2/HBM misses that need deep MLP. The
    // h-loads (+512B, line-shared with neighbor waves -> L1 hits) are NOT
    // pinned so their registers are short-lived transients.
    const float4 m0 = ld4(mask + mb);
    const float4 md = ld4(mask + mb + od);
    float4 P0[3], T0[3], PD[3], TD[3];
#pragma unroll
    for (int c = 0; c < 3; ++c) {
        const int pb = pb0 + c * 2097152;
        P0[c] = ld4(pred + pb);       T0[c] = ld4(target + pb);
        PD[c] = ld4(pred + pb + od);  TD[c] = ld4(target + pb + od);
    }
    __builtin_amdgcn_sched_barrier(0);   // far loads may not sink past here

    const float4 mh = ld4(mask + mb + oh);   // short-latency, unpinned

    const float m4w = __shfl_down(m0.x, 1, 64);  // lane w4=31: garbage, wv=0

    // pairwise mins (binary mask -> AND); boundary flags kill clamped terms
    const float mz0 = fminf(m0.x, m0.y), mz1 = fminf(m0.y, m0.z),
                mz2 = fminf(m0.z, m0.w), mz3 = fminf(m0.w, m4w) * wv;
    const float my0 = fminf(m0.x, mh.x) * hv, my1 = fminf(m0.y, mh.y) * hv,
                my2 = fminf(m0.z, mh.z) * hv, my3 = fminf(m0.w, mh.w) * hv;
    const float mx0 = fminf(m0.x, md.x) * dv, mx1 = fminf(m0.y, md.y) * dv,
                mx2 = fminf(m0.z, md.z) * dv, mx3 = fminf(m0.w, md.w) * dv;

    acc[0] = m0.x + m0.y + m0.z + m0.w;
    acc[1] = mx0 + mx1 + mx2 + mx3;
    acc[2] = my0 + my1 + my2 + my3;
    acc[3] = mz0 + mz1 + mz2 + mz3;

#pragma unroll
    for (int c = 0; c < 3; ++c) {
        const int pb = pb0 + c * 2097152;
        const float4 ph = ld4(pred + pb + oh);     // unpinned, L1-hit
        const float4 th = ld4(target + pb + oh);
        const float4 p0 = P0[c], t0 = T0[c];
        const float4 pd = PD[c], td = TD[c];
        const float  p4 = __shfl_down(p0.x, 1, 64);  // w-neighbor from lane+1
        const float  t4 = __shfl_down(t0.x, 1, 64);

        const float e0x = p0.x - t0.x, e0y = p0.y - t0.y,
                    e0z = p0.z - t0.z, e0w = p0.w - t0.w;
        const float e4  = p4 - t4;

        acc[4] += fabsf(e0x)*m0.x + fabsf(e0y)*m0.y
                + fabsf(e0z)*m0.z + fabsf(e0w)*m0.w;
        acc[5] += e0x*e0x*m0.x + e0y*e0y*m0.y
                + e0z*e0z*m0.z + e0w*e0w*m0.w;
        acc[6] += fabsf(p0.x)*(1.f-m0.x) + fabsf(p0.y)*(1.f-m0.y)
                + fabsf(p0.z)*(1.f-m0.z) + fabsf(p0.w)*(1.f-m0.w);

        // W direction (reference dz); mz3=0 at w-boundary kills shfl garbage
        acc[9]  += fabsf(e0y-e0x)*mz0 + fabsf(e0z-e0y)*mz1
                 + fabsf(e0w-e0z)*mz2 + fabsf(e4 -e0w)*mz3;
        acc[12] += fabsf(p0.y-p0.x)*mz0 + fabsf(p0.z-p0.y)*mz1
                 + fabsf(p0.w-p0.z)*mz2 + fabsf(p4  -p0.w)*mz3;

        // H direction (reference dy); my*=0 at h-boundary
        acc[8]  += fabsf((ph.x-th.x)-e0x)*my0 + fabsf((ph.y-th.y)-e0y)*my1
                 + fabsf((ph.z-th.z)-e0z)*my2 + fabsf((ph.w-th.w)-e0w)*my3;
        acc[11] += fabsf(ph.x-p0.x)*my0 + fabsf(ph.y-p0.y)*my1
                 + fabsf(ph.z-p0.z)*my2 + fabsf(ph.w-p0.w)*my3;

        // D direction (reference dx); mx*=0 at d-boundary
        acc[7]  += fabsf((pd.x-td.x)-e0x)*mx0 + fabsf((pd.y-td.y)-e0y)*mx1
                 + fabsf((pd.z-td.z)-e0z)*mx2 + fabsf((pd.w-td.w)-e0w)*mx3;
        acc[10] += fabsf(pd.x-p0.x)*mx0 + fabsf(pd.y-p0.y)*mx1
                 + fabsf(pd.z-p0.z)*mx2 + fabsf(pd.w-p0.w)*mx3;
    }

    // per-wave shuffle reduce -> own partials row; NO __syncthreads:
    // each wave retires as soon as its own tail drains.
    const int lane = threadIdx.x & 63;
    const int wave = threadIdx.x >> 6;
    float mine = 0.f;   // lane k (<16) ends up holding total of acc[k]
#pragma unroll
    for (int k = 0; k < NACC; ++k) {
        float v = acc[k];
        for (int o = 32; o > 0; o >>= 1) v += __shfl_down(v, o, 64);
        const float tot = __shfl(v, 0, 64);
        if (lane == k) mine = tot;
    }
    if (lane < NPAD)
        partials[(blockIdx.x * 4 + wave) * NPAD + lane] = mine; // pad rows=0
}

// Level 1: 64 blocks x 256 threads; thread r reads row r (4 independent
// float4), block-reduces 256 rows -> 1 row. 64 CUs share the 1 MiB read.
__global__ __launch_bounds__(256) void loss_mid(
    const float* __restrict__ partials, float* __restrict__ mid)
{
    const int r = blockIdx.x * 256 + threadIdx.x;   // exactly covers 16384
    const float* row = partials + r * NPAD;
    const float4 r0 = ld4(row);     const float4 r1 = ld4(row + 4);
    const float4 r2 = ld4(row + 8); const float4 r3 = ld4(row + 12);
    float acc[NPAD] = {r0.x, r0.y, r0.z, r0.w, r1.x, r1.y, r1.z, r1.w,
                       r2.x, r2.y, r2.z, r2.w, r3.x, r3.y, r3.z, r3.w};

    const int lane = threadIdx.x & 63;
    const int wave = threadIdx.x >> 6;
    __shared__ float red[4][NPAD];
#pragma unroll
    for (int k = 0; k < NPAD; ++k) {
        float v = acc[k];
        for (int o = 32; o > 0; o >>= 1) v += __shfl_down(v, o, 64);
        if (lane == 0) red[wave][k] = v;
    }
    __syncthreads();
    if (threadIdx.x < NPAD) {
        const int k = threadIdx.x;
        mid[blockIdx.x * NPAD + k] =
            red[0][k] + red[1][k] + red[2][k] + red[3][k];
    }
}

// Level 2: one wave; lane l reads mid row l (64 rows), shuffle-reduce,
// lane 0 does the scalar epilogue.
__global__ __launch_bounds__(64) void loss_final(
    const float* __restrict__ mid, float* __restrict__ out)
{
    const int lane = threadIdx.x;
    float acc[NPAD];
    {
        const float* row = mid + lane * NPAD;   // lane < 64 == NMID
        const float4 r0 = ld4(row);     const float4 r1 = ld4(row + 4);
        const float4 r2 = ld4(row + 8); const float4 r3 = ld4(row + 12);
        acc[0] = r0.x;  acc[1] = r0.y;  acc[2] = r0.z;  acc[3] = r0.w;
        acc[4] = r1.x;  acc[5] = r1.y;  acc[6] = r1.z;  acc[7] = r1.w;
        acc[8] = r2.x;  acc[9] = r2.y;  acc[10] = r2.z; acc[11] = r2.w;
        acc[12] = r3.x; acc[13] = r3.y; acc[14] = r3.z; acc[15] = r3.w;
    }
#pragma unroll
    for (int k = 0; k < NACC; ++k) {
        for (int o = 32; o > 0; o >>= 1) acc[k] += __shfl_down(acc[k], o, 64);
    }
    if (lane == 0) {
        const float EPS = 1e-8f;
        const float M = acc[0], Mx = acc[1], My = acc[2], Mz = acc[3];
        float loss = (acc[4] + acc[5]) / (3.f * M + EPS);   // W_MAE=1, W_MSE=1
        loss += 0.1f   * (acc[7] / (3.f*Mx + EPS) + acc[8] / (3.f*My + EPS)
                        + acc[9] / (3.f*Mz + EPS));
        loss += 0.002f * (acc[10] / (3.f*Mx + EPS) + acc[11] / (3.f*My + EPS)
                        + acc[12] / (3.f*Mz + EPS));
        const float inv = 4194304.f - M;  // B*D*H*W - M
        loss += 0.15f * acc[6] / (3.f * inv + EPS);
        out[0] = loss;
    }
}

extern "C" void kernel_launch(void* const* d_in, const int* in_sizes, int n_in,
                              void* d_out, int out_size, void* d_ws, size_t ws_size,
                              hipStream_t stream) {
    const float* pred   = (const float*)d_in[0];
    const float* target = (const float*)d_in[1];
    const float* mask   = (const float*)d_in[2];
    float* out      = (float*)d_out;
    float* partials = (float*)d_ws;                 // 16384*16 floats = 1 MiB
    float* mid      = partials + NROWS * NPAD;      // 64*16 floats

    loss_main<<<NBLOCKS, 256, 0, stream>>>(pred, target, mask, partials);
    loss_mid<<<NMID, 256, 0, stream>>>(partials, mid);
    loss_final<<<1, 64, 0, stream>>>(mid, out);
}

// Round 9
// 142.106 us; speedup vs baseline: 1.1804x; 1.0177x over previous
//
#include <hip/hip_runtime.h>

// CompositeLoss R20 == R15 (terminal revert to session best, 139.8us).
// Final map (R14-R19): demand-read BW is pinned at 1.5-1.9 TB/s chip-wide
// (~6-7 GB/s/CU) invariant to occupancy 19->56% and per-wave MLP 3->21
// outstanding f4 -- consistent with a fixed per-CU outstanding-miss
// capacity (~36-40 x 64B lines / ~400ns). FETCH ~65MB is the L3-filtered
// unique-data floor; 65MB / 1.6TB/s = the measured ~40us. Stream budget:
// ~83us harness poison fills (fixed) + ~40us loss_main (at the miss-
// concurrency wall) + ~17us reduce/launch tail (no init-free fusion
// possible under workspace poisoning). R15's all-pin (sched_barrier(0)
// after all 21 f4 loads, launch_bounds(256,3)) was the best measured
// variant: 45 -> ~40us on loss_main vs the compiler-sunk schedule.
//  0:M 1:Mx(d) 2:My(h) 3:Mz(w)  4:Smae 5:Smse 6:Sbg
//  7:Sgx 8:Sgy 9:Sgz  10:Stx 11:Sty 12:Stz
#define NACC 13
#define NPAD 16
#define NBLOCKS 4096   // 2^20 groups / 256
#define NROWS 16384    // NBLOCKS * 4 waves
#define NMID 64        // 16384 / 256

__device__ __forceinline__ float4 ld4(const float* p) {
    return *reinterpret_cast<const float4*>(p);
}

__global__ __launch_bounds__(256, 3) void loss_main(
    const float* __restrict__ pred, const float* __restrict__ target,
    const float* __restrict__ mask, float* __restrict__ partials)
{
    float acc[NACC];
#pragma unroll
    for (int k = 0; k < NACC; ++k) acc[k] = 0.f;

    // one group per thread: group = (b, d, h, w4); mapping identical to R11
    const int g  = blockIdx.x * 256 + threadIdx.x;
    const int w4 = g & 31;
    const int h  = (g >> 5) & 127;
    const int d  = (g >> 12) & 127;
    const int b  = g >> 19;
    const int w  = w4 << 2;
    const int mb  = b * 2097152 + d * 16384 + h * 128 + w; // mask index
    const int pb0 = b * 6291456 + d * 16384 + h * 128 + w; // pred/target base

    // boundary: clamp offsets in-bounds; flags zero the affected masks
    const float wv = (w4 < 31) ? 1.f : 0.f;
    const float hv = (h < 127) ? 1.f : 0.f;
    const float dv = (d < 127) ? 1.f : 0.f;
    const int oh = (h < 127) ? 128   : 0;
    const int od = (d < 127) ? 16384 : 0;

    // ---- issue ALL 21 float4 loads, then PIN them with sched_barrier(0):
    // the scheduler may not sink any load past the barrier, so every load
    // is outstanding before the first compute waits on it.
    const float4 m0 = ld4(mask + mb);
    const float4 mh = ld4(mask + mb + oh);
    const float4 md = ld4(mask + mb + od);
    float4 P0[3], T0[3], PH[3], TH[3], PD[3], TD[3];
#pragma unroll
    for (int c = 0; c < 3; ++c) {
        const int pb = pb0 + c * 2097152;
        P0[c] = ld4(pred + pb);
        T0[c] = ld4(target + pb);
        PD[c] = ld4(pred + pb + od);     // long-latency (L2/L3, +64KB)
        TD[c] = ld4(target + pb + od);
        PH[c] = ld4(pred + pb + oh);     // likely L1 (neighbor thread's row)
        TH[c] = ld4(target + pb + oh);
    }
    __builtin_amdgcn_sched_barrier(0);   // <- loads may not sink past here

    const float m4w = __shfl_down(m0.x, 1, 64);  // lane w4=31: garbage, wv=0

    // pairwise mins (binary mask -> AND); boundary flags kill clamped terms
    const float mz0 = fminf(m0.x, m0.y), mz1 = fminf(m0.y, m0.z),
                mz2 = fminf(m0.z, m0.w), mz3 = fminf(m0.w, m4w) * wv;
    const float my0 = fminf(m0.x, mh.x) * hv, my1 = fminf(m0.y, mh.y) * hv,
                my2 = fminf(m0.z, mh.z) * hv, my3 = fminf(m0.w, mh.w) * hv;
    const float mx0 = fminf(m0.x, md.x) * dv, mx1 = fminf(m0.y, md.y) * dv,
                mx2 = fminf(m0.z, md.z) * dv, mx3 = fminf(m0.w, md.w) * dv;

    acc[0] = m0.x + m0.y + m0.z + m0.w;
    acc[1] = mx0 + mx1 + mx2 + mx3;
    acc[2] = my0 + my1 + my2 + my3;
    acc[3] = mz0 + mz1 + mz2 + mz3;

#pragma unroll
    for (int c = 0; c < 3; ++c) {
        const float4 p0 = P0[c], t0 = T0[c];
        const float4 ph = PH[c], th = TH[c];
        const float4 pd = PD[c], td = TD[c];
        const float  p4 = __shfl_down(p0.x, 1, 64);  // w-neighbor from lane+1
        const float  t4 = __shfl_down(t0.x, 1, 64);

        const float e0x = p0.x - t0.x, e0y = p0.y - t0.y,
                    e0z = p0.z - t0.z, e0w = p0.w - t0.w;
        const float e4  = p4 - t4;

        acc[4] += fabsf(e0x)*m0.x + fabsf(e0y)*m0.y
                + fabsf(e0z)*m0.z + fabsf(e0w)*m0.w;
        acc[5] += e0x*e0x*m0.x + e0y*e0y*m0.y
                + e0z*e0z*m0.z + e0w*e0w*m0.w;
        acc[6] += fabsf(p0.x)*(1.f-m0.x) + fabsf(p0.y)*(1.f-m0.y)
                + fabsf(p0.z)*(1.f-m0.z) + fabsf(p0.w)*(1.f-m0.w);

        // W direction (reference dz); mz3=0 at w-boundary kills shfl garbage
        acc[9]  += fabsf(e0y-e0x)*mz0 + fabsf(e0z-e0y)*mz1
                 + fabsf(e0w-e0z)*mz2 + fabsf(e4 -e0w)*mz3;
        acc[12] += fabsf(p0.y-p0.x)*mz0 + fabsf(p0.z-p0.y)*mz1
                 + fabsf(p0.w-p0.z)*mz2 + fabsf(p4  -p0.w)*mz3;

        // H direction (reference dy); my*=0 at h-boundary
        acc[8]  += fabsf((ph.x-th.x)-e0x)*my0 + fabsf((ph.y-th.y)-e0y)*my1
                 + fabsf((ph.z-th.z)-e0z)*my2 + fabsf((ph.w-th.w)-e0w)*my3;
        acc[11] += fabsf(ph.x-p0.x)*my0 + fabsf(ph.y-p0.y)*my1
                 + fabsf(ph.z-p0.z)*my2 + fabsf(ph.w-p0.w)*my3;

        // D direction (reference dx); mx*=0 at d-boundary
        acc[7]  += fabsf((pd.x-td.x)-e0x)*mx0 + fabsf((pd.y-td.y)-e0y)*mx1
                 + fabsf((pd.z-td.z)-e0z)*mx2 + fabsf((pd.w-td.w)-e0w)*mx3;
        acc[10] += fabsf(pd.x-p0.x)*mx0 + fabsf(pd.y-p0.y)*mx1
                 + fabsf(pd.z-p0.z)*mx2 + fabsf(pd.w-p0.w)*mx3;
    }

    // per-wave shuffle reduce -> own partials row; NO __syncthreads:
    // each wave retires as soon as its own tail drains.
    const int lane = threadIdx.x & 63;
    const int wave = threadIdx.x >> 6;
    float mine = 0.f;   // lane k (<16) ends up holding total of acc[k]
#pragma unroll
    for (int k = 0; k < NACC; ++k) {
        float v = acc[k];
        for (int o = 32; o > 0; o >>= 1) v += __shfl_down(v, o, 64);
        const float tot = __shfl(v, 0, 64);
        if (lane == k) mine = tot;
    }
    if (lane < NPAD)
        partials[(blockIdx.x * 4 + wave) * NPAD + lane] = mine; // pad rows=0
}

// Level 1: 64 blocks x 256 threads; thread r reads row r (4 independent
// float4), block-reduces 256 rows -> 1 row. 64 CUs share the 1 MiB read.
__global__ __launch_bounds__(256) void loss_mid(
    const float* __restrict__ partials, float* __restrict__ mid)
{
    const int r = blockIdx.x * 256 + threadIdx.x;   // exactly covers 16384
    const float* row = partials + r * NPAD;
    const float4 r0 = ld4(row);     const float4 r1 = ld4(row + 4);
    const float4 r2 = ld4(row + 8); const float4 r3 = ld4(row + 12);
    float acc[NPAD] = {r0.x, r0.y, r0.z, r0.w, r1.x, r1.y, r1.z, r1.w,
                       r2.x, r2.y, r2.z, r2.w, r3.x, r3.y, r3.z, r3.w};

    const int lane = threadIdx.x & 63;
    const int wave = threadIdx.x >> 6;
    __shared__ float red[4][NPAD];
#pragma unroll
    for (int k = 0; k < NPAD; ++k) {
        float v = acc[k];
        for (int o = 32; o > 0; o >>= 1) v += __shfl_down(v, o, 64);
        if (lane == 0) red[wave][k] = v;
    }
    __syncthreads();
    if (threadIdx.x < NPAD) {
        const int k = threadIdx.x;
        mid[blockIdx.x * NPAD + k] =
            red[0][k] + red[1][k] + red[2][k] + red[3][k];
    }
}

// Level 2: one wave; lane l reads mid row l (64 rows), shuffle-reduce,
// lane 0 does the scalar epilogue.
__global__ __launch_bounds__(64) void loss_final(
    const float* __restrict__ mid, float* __restrict__ out)
{
    const int lane = threadIdx.x;
    float acc[NPAD];
    {
        const float* row = mid + lane * NPAD;   // lane < 64 == NMID
        const float4 r0 = ld4(row);     const float4 r1 = ld4(row + 4);
        const float4 r2 = ld4(row + 8); const float4 r3 = ld4(row + 12);
        acc[0] = r0.x;  acc[1] = r0.y;  acc[2] = r0.z;  acc[3] = r0.w;
        acc[4] = r1.x;  acc[5] = r1.y;  acc[6] = r1.z;  acc[7] = r1.w;
        acc[8] = r2.x;  acc[9] = r2.y;  acc[10] = r2.z; acc[11] = r2.w;
        acc[12] = r3.x; acc[13] = r3.y; acc[14] = r3.z; acc[15] = r3.w;
    }
#pragma unroll
    for (int k = 0; k < NACC; ++k) {
        for (int o = 32; o > 0; o >>= 1) acc[k] += __shfl_down(acc[k], o, 64);
    }
    if (lane == 0) {
        const float EPS = 1e-8f;
        const float M = acc[0], Mx = acc[1], My = acc[2], Mz = acc[3];
        float loss = (acc[4] + acc[5]) / (3.f * M + EPS);   // W_MAE=1, W_MSE=1
        loss += 0.1f   * (acc[7] / (3.f*Mx + EPS) + acc[8] / (3.f*My + EPS)
                        + acc[9] / (3.f*Mz + EPS));
        loss += 0.002f * (acc[10] / (3.f*Mx + EPS) + acc[11] / (3.f*My + EPS)
                        + acc[12] / (3.f*Mz + EPS));
        const float inv = 4194304.f - M;  // B*D*H*W - M
        loss += 0.15f * acc[6] / (3.f * inv + EPS);
        out[0] = loss;
    }
}

extern "C" void kernel_launch(void* const* d_in, const int* in_sizes, int n_in,
                              void* d_out, int out_size, void* d_ws, size_t ws_size,
                              hipStream_t stream) {
    const float* pred   = (const float*)d_in[0];
    const float* target = (const float*)d_in[1];
    const float* mask   = (const float*)d_in[2];
    float* out      = (float*)d_out;
    float* partials = (float*)d_ws;                 // 16384*16 floats = 1 MiB
    float* mid      = partials + NROWS * NPAD;      // 64*16 floats

    loss_main<<<NBLOCKS, 256, 0, stream>>>(pred, target, mask, partials);
    loss_mid<<<NMID, 256, 0, stream>>>(partials, mid);
    loss_final<<<1, 64, 0, stream>>>(mid, out);
}